// Round 13
// baseline (291.017 us; speedup 1.0000x reference)
//
#include <hip/hip_runtime.h>

namespace {

constexpr int BB = 2048;   // batch
constexpr int TT = 256;    // time steps
constexpr float L2E = 1.4426950408889634f;  // log2(e)

typedef __attribute__((ext_vector_type(8))) short bf8;          // 8 bf16 (4 VGPR)
typedef __attribute__((ext_vector_type(4))) float f4;           // MFMA acc
typedef __attribute__((ext_vector_type(2))) unsigned int u32x2;

#define MFMA16(a, b, c) __builtin_amdgcn_mfma_f32_16x16x32_bf16((a), (b), (c), 0, 0, 0)

__device__ __forceinline__ unsigned short f2bf_rne(float f) {
  unsigned int x = __float_as_uint(f);
  return (unsigned short)((x + 0x7fffu + ((x >> 16) & 1u)) >> 16);
}
__device__ __forceinline__ void mk_hilo(float v, short& hi, short& lo) {
  unsigned int u = __float_as_uint(v);
  hi = (short)(u >> 16);
  float r = v - __uint_as_float(u & 0xffff0000u);
  lo = (short)(__float_as_uint(r) >> 16);
}

// ============ all 4 GRU layers, lockstep pipeline with SKEW-2 ============
// 1024 threads = 16 waves = 4 quads; quad g = layer g at step t = slot - 2g.
// One __syncthreads per slot. Inter-layer skew of 2 slots means producer data
// is >=1 barrier old -> consumer PREFETCHES y(t+1) into registers during slot
// t; post-barrier the x-MFMAs issue immediately (no LDS wait), covering the
// h ds_read latency with independent MFMA work. h-state ring of 4 slots per
// layer, fragment-major [u>>3][n][u&7] (conflict-free b128). Ring slot (t+1)&3
// holds H(t+1) = y(t). Hazards: self-h RAW 1 barrier; producer->prefetch RAW
// 1 barrier; ring WAR margin 2-3 barriers. Gates pre-scaled by log2e (R,Z) /
// 2log2e (N) -> raw v_exp_f32; R/Z share one reciprocal.
__global__ __launch_bounds__(1024, 4) void gru_all(
    const float* __restrict__ xs, const float* __restrict__ xp,
    const float* __restrict__ W0s, const float* __restrict__ W0p,
    const float* __restrict__ Wihs, const float* __restrict__ Wihp,  // [3][192][64]
    const float* __restrict__ Whhs, const float* __restrict__ Whhp,  // [4][192][64]
    const float* __restrict__ bihs, const float* __restrict__ bihp,  // [4][192]
    const float* __restrict__ bhhs, const float* __restrict__ bhhp,
    float* __restrict__ hlast) {
  const int tid = threadIdx.x;
  const int Wv = tid >> 6, lane = tid & 63;
  const int g = Wv >> 2, w = Wv & 3;      // quad (=layer), wave-in-quad
  const int n15 = lane & 15, q = lane >> 4;
  const int blk = blockIdx.x, stack = blk >> 7;
  const int b0 = (blk & 127) * 16;

  const float* Wh = (stack ? Whhp : Whhs) + (size_t)g * 192 * 64;
  const float* bi = (stack ? bihp : bihs) + g * 192;
  const float* bh = (stack ? bhhp : bhhs) + g * 192;
  const float* Wx = (stack ? Wihp : Wihs) + (size_t)(g - 1) * 192 * 64;  // g>=1

  // [g][slot][frag=u>>3][n][elem=u&7]
  __shared__ unsigned short hb[4][4][8][16][8];

  for (int e = tid; e < 4 * 4 * 8 * 16 * 8; e += 1024)
    ((unsigned short*)hb)[e] = 0;

  const int mrow = 16 * w + n15;   // A-frag row; wave w owns Mtiles {w, w+4, w+8}
  const int mu = 16 * w + 4 * q;   // C-layout unit base for this lane's 4 regs
  const int fr_w = 2 * w + (q >> 1);  // write frag row
  const int eo_w = (q & 1) * 4;       // write elem offset

  // per-gate pre-scale: R,Z by log2e; N by 2*log2e
  const float gsc[3] = {L2E, L2E, 2.f * L2E};

  // ---- Wh fragments: rne bf16 of (scale * W) ----
  bf8 whh_[3][2];
  #pragma unroll
  for (int i = 0; i < 3; ++i) {
    #pragma unroll
    for (int kt = 0; kt < 2; ++kt) {
      const float* ph_ = Wh + (size_t)(i * 64 + mrow) * 64 + kt * 32 + q * 8;
      f4 ha = *(const f4*)ph_, hc = *(const f4*)(ph_ + 4);
      bf8 h2;
      #pragma unroll
      for (int j = 0; j < 8; ++j)
        h2[j] = (short)f2bf_rne(gsc[i] * ((j < 4) ? ha[j] : hc[j - 4]));
      whh_[i][kt] = h2;
    }
  }
  // ---- Wx fragments ----
  bf8 wxh_[3][2];
  if (g >= 1) {
    #pragma unroll
    for (int i = 0; i < 3; ++i) {
      #pragma unroll
      for (int kt = 0; kt < 2; ++kt) {
        const float* px_ = Wx + (size_t)(i * 64 + mrow) * 64 + kt * 32 + q * 8;
        f4 xa = *(const f4*)px_, xc = *(const f4*)(px_ + 4);
        bf8 h1;
        #pragma unroll
        for (int j = 0; j < 8; ++j)
          h1[j] = (short)f2bf_rne(gsc[i] * ((j < 4) ? xa[j] : xc[j - 4]));
        wxh_[i][kt] = h1;
      }
    }
  } else {
    // layer 0: scaled W0 trunc-hi/lo packed in one K=32 frag (see R6 comment).
    const float* W0 = stack ? W0p : W0s;
    #pragma unroll
    for (int i = 0; i < 3; ++i) {
      bf8 a;
      #pragma unroll
      for (int j = 0; j < 8; ++j) a[j] = 0;
      if (q == 0) {
        if (stack) {
          #pragma unroll
          for (int d = 0; d < 4; ++d) {
            short hi, lo;
            mk_hilo(gsc[i] * W0[(size_t)(i * 64 + mrow) * 4 + d], hi, lo);
            a[d] = hi; a[4 + d] = lo;
          }
        } else {
          short hi, lo; mk_hilo(gsc[i] * W0[i * 64 + mrow], hi, lo);
          a[0] = hi; a[1] = hi; a[4] = lo; a[5] = lo;
        }
      }
      wxh_[i][0] = a; wxh_[i][1] = a;
    }
  }

  f4 bR, bZ, bNx, bNh;
  #pragma unroll
  for (int r = 0; r < 4; ++r) {
    bR[r]  = L2E * (bi[mu + r] + bh[mu + r]);
    bZ[r]  = L2E * (bi[64 + mu + r] + bh[64 + mu + r]);
    bNx[r] = 2.f * L2E * bi[128 + mu + r];
    bNh[r] = 2.f * L2E * bh[128 + mu + r];
  }
  f4 h = {0.f, 0.f, 0.f, 0.f};

  // ring-slot pointer tables, indexed by slot literal S = s&3 (skew 2g):
  // t = s - 2g; read h(t) at t&3; write H(t+1) at (t+1)&3; prefetch producer
  // H(t+2) (= y(t+1)) at (t+2)&3.
  const unsigned short* rs0[4];
  unsigned short* ws0[4];
  const unsigned short* rp0[4];
  #pragma unroll
  for (int j = 0; j < 4; ++j) {
    rs0[j] = &hb[g][(j - 2 * g) & 3][q][n15][0];
    ws0[j] = &hb[g][(j - 2 * g + 1) & 3][fr_w][n15][eo_w];
    rp0[j] = &hb[(g >= 1 ? g - 1 : 0)][(j - 2 * g + 2) & 3][q][n15][0];
  }

  // layer-0 per-lane x prefetch (batch row b0+n15)
  const size_t xrow = (size_t)(b0 + n15);
  float px0 = 0.f, px1 = 0.f, px2 = 0.f, px3 = 0.f;
  if (g == 0) {
    if (stack) { f4 t4 = *(const f4*)(xp + xrow * TT * 4); px0 = t4[0]; px1 = t4[1]; px2 = t4[2]; px3 = t4[3]; }
    else       { px0 = xs[xrow * TT]; }
  }
  bf8 xpf0 = {}, xpf1 = {};   // prefetched producer y fragments
  __syncthreads();

// One slot. S = slot&3 literal; GD = 1 for guarded prologue/epilogue.
#define GRU_STEP(S, GD)                                                        \
  {                                                                            \
    const int tc = s + (S) - 2 * g;                                            \
    if (!(GD) || (unsigned)tc < (unsigned)TT) {                                \
      bf8 hh0 = *(const bf8*)rs0[S];                                           \
      bf8 hh1 = *(const bf8*)(rs0[S] + 512);                                   \
      f4 aR = bR, aZ = bZ, aNx = bNx, aNh = bNh;                               \
      if (g == 0) {                                                            \
        bf8 xq;                                                                \
        _Pragma("unroll") for (int j = 0; j < 8; ++j) xq[j] = 0;               \
        if (q == 0) {                                                          \
          if (stack) {                                                         \
            short a0 = (short)f2bf_rne(px0), a1 = (short)f2bf_rne(px1);        \
            short a2 = (short)f2bf_rne(px2), a3 = (short)f2bf_rne(px3);        \
            xq[0] = a0; xq[1] = a1; xq[2] = a2; xq[3] = a3;                    \
            xq[4] = a0; xq[5] = a1; xq[6] = a2; xq[7] = a3;                    \
          } else {                                                             \
            unsigned short xh = f2bf_rne(px0);                                 \
            float xf = __uint_as_float((unsigned)xh << 16);                    \
            unsigned short xl = f2bf_rne(px0 - xf);                            \
            xq[0] = (short)xh; xq[1] = (short)xl;                              \
            xq[4] = (short)xh; xq[5] = (short)xl;                              \
          }                                                                    \
        }                                                                      \
        __builtin_amdgcn_s_setprio(1);                                         \
        aR  = MFMA16(wxh_[0][0], xq, aR);                                      \
        aZ  = MFMA16(wxh_[1][0], xq, aZ);                                      \
        aNx = MFMA16(wxh_[2][0], xq, aNx);                                     \
        aR  = MFMA16(whh_[0][0], hh0, aR);  aR  = MFMA16(whh_[0][1], hh1, aR); \
        aZ  = MFMA16(whh_[1][0], hh0, aZ);  aZ  = MFMA16(whh_[1][1], hh1, aZ); \
        aNh = MFMA16(whh_[2][0], hh0, aNh); aNh = MFMA16(whh_[2][1], hh1, aNh);\
        __builtin_amdgcn_s_setprio(0);                                         \
        if (!(GD) || tc + 1 < TT) {                                            \
          if (stack) { f4 t4 = *(const f4*)(xp + (xrow * TT + tc + 1) * 4);    \
                       px0 = t4[0]; px1 = t4[1]; px2 = t4[2]; px3 = t4[3]; }   \
          else       { px0 = xs[xrow * TT + tc + 1]; }                         \
        }                                                                      \
      } else {                                                                 \
        /* x-MFMAs from prefetched regs: issue before h ds_read completes */   \
        __builtin_amdgcn_s_setprio(1);                                         \
        aR  = MFMA16(wxh_[0][0], xpf0, aR);  aR  = MFMA16(wxh_[0][1], xpf1, aR);  \
        aZ  = MFMA16(wxh_[1][0], xpf0, aZ);  aZ  = MFMA16(wxh_[1][1], xpf1, aZ);  \
        aNx = MFMA16(wxh_[2][0], xpf0, aNx); aNx = MFMA16(wxh_[2][1], xpf1, aNx); \
        aR  = MFMA16(whh_[0][0], hh0, aR);  aR  = MFMA16(whh_[0][1], hh1, aR); \
        aZ  = MFMA16(whh_[1][0], hh0, aZ);  aZ  = MFMA16(whh_[1][1], hh1, aZ); \
        aNh = MFMA16(whh_[2][0], hh0, aNh); aNh = MFMA16(whh_[2][1], hh1, aNh);\
        __builtin_amdgcn_s_setprio(0);                                         \
      }                                                                        \
      _Pragma("unroll") for (int r = 0; r < 4; ++r) {                          \
        float eR = __builtin_amdgcn_exp2f(-aR[r]);                             \
        float eZ = __builtin_amdgcn_exp2f(-aZ[r]);                             \
        float dR = 1.f + eR, dZ = 1.f + eZ;                                    \
        float qq = __builtin_amdgcn_rcpf(dR * dZ);                             \
        float rr = dZ * qq;   /* sigmoid(aR) */                                \
        float zz = dR * qq;   /* sigmoid(aZ) */                                \
        float eN = __builtin_amdgcn_exp2f(aNx[r] + rr * aNh[r]);               \
        float nn = 1.f - 2.f * __builtin_amdgcn_rcpf(eN + 1.f);                \
        h[r] = nn + zz * (h[r] - nn);                                          \
      }                                                                        \
      unsigned p01, p23;                                                       \
      asm("v_cvt_pk_bf16_f32 %0, %1, %2" : "=v"(p01) : "v"(h[0]), "v"(h[1])); \
      asm("v_cvt_pk_bf16_f32 %0, %1, %2" : "=v"(p23) : "v"(h[2]), "v"(h[3])); \
      u32x2 hiw = {p01, p23};                                                  \
      *(u32x2*)ws0[S] = hiw;                                                   \
      if (g == 3 && tc == TT - 1)                                              \
        *(f4*)&hlast[((size_t)stack * BB + b0 + n15) * 64 + mu] = h;           \
    }                                                                          \
    if (g >= 1) {                                                              \
      const int tn_ = s + (S) - 2 * g + 1;                                     \
      if (!(GD) || (unsigned)tn_ < (unsigned)TT) {                             \
        xpf0 = *(const bf8*)rp0[S];                                            \
        xpf1 = *(const bf8*)(rp0[S] + 512);                                    \
      }                                                                        \
    }                                                                          \
    __syncthreads();                                                           \
  }

  // prologue: slots 0..7 (guarded)
  for (int s = 0; s < 8; s += 4) {
    GRU_STEP(0, 1) GRU_STEP(1, 1) GRU_STEP(2, 1) GRU_STEP(3, 1)
  }
  // steady: slots 8..251 — all quads active, no guards
  for (int s = 8; s < 252; s += 4) {
    GRU_STEP(0, 0) GRU_STEP(1, 0) GRU_STEP(2, 0) GRU_STEP(3, 0)
  }
  // epilogue: slots 252..263 (guarded; quad 3 finishes t=255 at slot 261)
  for (int s = 252; s < 264; s += 4) {
    GRU_STEP(0, 1) GRU_STEP(1, 1) GRU_STEP(2, 1) GRU_STEP(3, 1)
  }
#undef GRU_STEP
}

// ---------------- FC head ----------------
__global__ __launch_bounds__(128) void head(
    const float* __restrict__ hlast,
    const float* __restrict__ W1, const float* __restrict__ b1,
    const float* __restrict__ g1, const float* __restrict__ be1,
    const float* __restrict__ m1, const float* __restrict__ v1,
    const float* __restrict__ W2, const float* __restrict__ b2,
    const float* __restrict__ g2, const float* __restrict__ be2,
    const float* __restrict__ m2, const float* __restrict__ v2,
    const float* __restrict__ W3, const float* __restrict__ b3,
    float* __restrict__ out) {
  const int b = blockIdx.x;
  const int j = threadIdx.x;
  __shared__ float xin[128];
  __shared__ float y1[128];
  __shared__ float y2[128];
  xin[j] = (j < 64) ? hlast[(size_t)b * 64 + j]
                    : hlast[(size_t)BB * 64 + (size_t)b * 64 + (j - 64)];
  __syncthreads();
  float acc = b1[j];
  #pragma unroll 8
  for (int k = 0; k < 128; ++k) acc = fmaf(W1[j * 128 + k], xin[k], acc);
  float sc = g1[j] * rsqrtf(v1[j] + 1e-5f);
  y1[j] = fmaxf(0.f, (acc - m1[j]) * sc + be1[j]);
  __syncthreads();
  acc = b2[j];
  #pragma unroll 8
  for (int k = 0; k < 128; ++k) acc = fmaf(W2[j * 128 + k], y1[k], acc);
  sc = g2[j] * rsqrtf(v2[j] + 1e-5f);
  y2[j] = fmaxf(0.f, (acc - m2[j]) * sc + be2[j]);
  __syncthreads();
  if (j < 2) {
    float a = b3[j];
    #pragma unroll 8
    for (int k = 0; k < 128; ++k) a = fmaf(W3[j * 128 + k], y2[k], a);
    out[(size_t)b * 2 + j] = a;
  }
}

}  // namespace

extern "C" void kernel_launch(void* const* d_in, const int* in_sizes, int n_in,
                              void* d_out, int out_size, void* d_ws, size_t ws_size,
                              hipStream_t stream) {
  (void)in_sizes; (void)n_in; (void)out_size; (void)ws_size;
  const float* sent   = (const float*)d_in[0];
  const float* price  = (const float*)d_in[1];
  const float* s_Wih0 = (const float*)d_in[2];
  const float* s_Wih  = (const float*)d_in[3];
  const float* s_Whh  = (const float*)d_in[4];
  const float* s_bih  = (const float*)d_in[5];
  const float* s_bhh  = (const float*)d_in[6];
  const float* p_Wih0 = (const float*)d_in[7];
  const float* p_Wih  = (const float*)d_in[8];
  const float* p_Whh  = (const float*)d_in[9];
  const float* p_bih  = (const float*)d_in[10];
  const float* p_bhh  = (const float*)d_in[11];
  const float* fc1_W  = (const float*)d_in[12];
  const float* fc1_b  = (const float*)d_in[13];
  const float* bn1_g  = (const float*)d_in[14];
  const float* bn1_b  = (const float*)d_in[15];
  const float* bn1_m  = (const float*)d_in[16];
  const float* bn1_v  = (const float*)d_in[17];
  const float* fc2_W  = (const float*)d_in[18];
  const float* fc2_b  = (const float*)d_in[19];
  const float* bn2_g  = (const float*)d_in[20];
  const float* bn2_b  = (const float*)d_in[21];
  const float* bn2_m  = (const float*)d_in[22];
  const float* bn2_v  = (const float*)d_in[23];
  const float* fc3_W  = (const float*)d_in[24];
  const float* fc3_b  = (const float*)d_in[25];
  float* out = (float*)d_out;

  float* hlast = (float*)d_ws;  // [2, B, 64] f32

  gru_all<<<dim3(256), dim3(1024), 0, stream>>>(
      sent, price, s_Wih0, p_Wih0, s_Wih, p_Wih, s_Whh, p_Whh,
      s_bih, p_bih, s_bhh, p_bhh, hlast);

  head<<<dim3(BB), dim3(128), 0, stream>>>(
      hlast, fc1_W, fc1_b, bn1_g, bn1_b, bn1_m, bn1_v,
      fc2_W, fc2_b, bn2_g, bn2_b, bn2_m, bn2_v, fc3_W, fc3_b, out);
}

// Round 14
// 282.397 us; speedup vs baseline: 1.0305x; 1.0305x over previous
//
#include <hip/hip_runtime.h>

namespace {

constexpr int BB = 2048;   // batch
constexpr int TT = 256;    // time steps
constexpr float L2E = 1.4426950408889634f;  // log2(e)

typedef __attribute__((ext_vector_type(8))) short bf8;          // 8 bf16 (4 VGPR)
typedef __attribute__((ext_vector_type(4))) float f4;           // MFMA acc
typedef __attribute__((ext_vector_type(2))) unsigned int u32x2;

#define MFMA16(a, b, c) __builtin_amdgcn_mfma_f32_16x16x32_bf16((a), (b), (c), 0, 0, 0)

__device__ __forceinline__ unsigned short f2bf_rne(float f) {
  unsigned int x = __float_as_uint(f);
  return (unsigned short)((x + 0x7fffu + ((x >> 16) & 1u)) >> 16);
}
__device__ __forceinline__ void mk_hilo(float v, short& hi, short& lo) {
  unsigned int u = __float_as_uint(v);
  hi = (short)(u >> 16);
  float r = v - __uint_as_float(u & 0xffff0000u);
  lo = (short)(__float_as_uint(r) >> 16);
}

// ACQUIRE poll of an LDS counter (wave-uniform address). Tight spin.
__device__ __forceinline__ void waitq(const unsigned* c, unsigned tgt) {
  while (__hip_atomic_load(c, __ATOMIC_ACQUIRE, __HIP_MEMORY_SCOPE_WORKGROUP) < tgt) {}
}

// ============ all 4 GRU layers, free-running pipelined in one block ============
// (R11 structure — best measured: 282.6 us total. R12 lockstep-barrier and R13
// skew-2-prefetch variants both measured equal or worse; the step time is
// pinned by VALU issue (gate transcendentals) + MFMA pipe, not sync.)
// 1024 threads = 16 waves = 4 quads; quad g = layer g. Sync via LDS sum-counters.
// h-state ring of 4 slots per layer, fragment-major [u>>3][n][u&7] (conflict-free
// b128 reads). Ring serves both self h-feedback (slot t&3) and next layer's x
// (slot (t+1)&3). Gates pre-scaled by log2e (R,Z) / 2log2e (N) -> raw v_exp_f32.
// x-path (producer wait + x-MFMAs) runs BEFORE the peer wait so it overlaps
// peers finishing step t-1; backpressure poll sits under the h-MFMA shadow;
// R/Z share one reciprocal (5 trans/pair instead of 6).
__global__ __launch_bounds__(1024, 4) void gru_all(
    const float* __restrict__ xs, const float* __restrict__ xp,
    const float* __restrict__ W0s, const float* __restrict__ W0p,
    const float* __restrict__ Wihs, const float* __restrict__ Wihp,  // [3][192][64]
    const float* __restrict__ Whhs, const float* __restrict__ Whhp,  // [4][192][64]
    const float* __restrict__ bihs, const float* __restrict__ bihp,  // [4][192]
    const float* __restrict__ bhhs, const float* __restrict__ bhhp,
    float* __restrict__ hlast) {
  const int tid = threadIdx.x;
  const int Wv = tid >> 6, lane = tid & 63;
  const int g = Wv >> 2, w = Wv & 3;      // quad (=layer), wave-in-quad
  const int n15 = lane & 15, q = lane >> 4;
  const int blk = blockIdx.x, stack = blk >> 7;
  const int b0 = (blk & 127) * 16;

  const float* Wh = (stack ? Whhp : Whhs) + (size_t)g * 192 * 64;
  const float* bi = (stack ? bihp : bihs) + g * 192;
  const float* bh = (stack ? bhhp : bhhs) + g * 192;
  const float* Wx = (stack ? Wihp : Wihs) + (size_t)(g - 1) * 192 * 64;  // g>=1

  // [g][slot][frag=u>>3][n][elem=u&7]
  __shared__ unsigned short hb[4][4][8][16][8];
  __shared__ unsigned qdone[4];

  for (int e = tid; e < 4 * 4 * 8 * 16 * 8; e += 1024)
    ((unsigned short*)hb)[e] = 0;
  if (tid < 4) qdone[tid] = 0;
  __syncthreads();  // only barrier in the kernel

  const int mrow = 16 * w + n15;   // A-frag row; wave w owns Mtiles {w, w+4, w+8}
  const int mu = 16 * w + 4 * q;   // C-layout unit base for this lane's 4 regs
  const int fr_w = 2 * w + (q >> 1);  // write frag row
  const int eo_w = (q & 1) * 4;       // write elem offset

  // per-gate pre-scale: R,Z by log2e; N by 2*log2e
  const float gsc[3] = {L2E, L2E, 2.f * L2E};

  // ---- Wh fragments: rne bf16 of (scale * W) ----
  bf8 whh_[3][2];
  #pragma unroll
  for (int i = 0; i < 3; ++i) {
    #pragma unroll
    for (int kt = 0; kt < 2; ++kt) {
      const float* ph_ = Wh + (size_t)(i * 64 + mrow) * 64 + kt * 32 + q * 8;
      f4 ha = *(const f4*)ph_, hc = *(const f4*)(ph_ + 4);
      bf8 h2;
      #pragma unroll
      for (int j = 0; j < 8; ++j)
        h2[j] = (short)f2bf_rne(gsc[i] * ((j < 4) ? ha[j] : hc[j - 4]));
      whh_[i][kt] = h2;
    }
  }
  // ---- Wx fragments ----
  bf8 wxh_[3][2];
  if (g >= 1) {
    #pragma unroll
    for (int i = 0; i < 3; ++i) {
      #pragma unroll
      for (int kt = 0; kt < 2; ++kt) {
        const float* px_ = Wx + (size_t)(i * 64 + mrow) * 64 + kt * 32 + q * 8;
        f4 xa = *(const f4*)px_, xc = *(const f4*)(px_ + 4);
        bf8 h1;
        #pragma unroll
        for (int j = 0; j < 8; ++j)
          h1[j] = (short)f2bf_rne(gsc[i] * ((j < 4) ? xa[j] : xc[j - 4]));
        wxh_[i][kt] = h1;
      }
    }
  } else {
    // layer 0: scaled W0 trunc-hi/lo packed in one K=32 frag (see R6 comment).
    const float* W0 = stack ? W0p : W0s;
    #pragma unroll
    for (int i = 0; i < 3; ++i) {
      bf8 a;
      #pragma unroll
      for (int j = 0; j < 8; ++j) a[j] = 0;
      if (q == 0) {
        if (stack) {
          #pragma unroll
          for (int d = 0; d < 4; ++d) {
            short hi, lo;
            mk_hilo(gsc[i] * W0[(size_t)(i * 64 + mrow) * 4 + d], hi, lo);
            a[d] = hi; a[4 + d] = lo;
          }
        } else {
          short hi, lo; mk_hilo(gsc[i] * W0[i * 64 + mrow], hi, lo);
          a[0] = hi; a[1] = hi; a[4] = lo; a[5] = lo;
        }
      }
      wxh_[i][0] = a; wxh_[i][1] = a;
    }
  }

  f4 bR, bZ, bNx, bNh;
  #pragma unroll
  for (int r = 0; r < 4; ++r) {
    bR[r]  = L2E * (bi[mu + r] + bh[mu + r]);
    bZ[r]  = L2E * (bi[64 + mu + r] + bh[64 + mu + r]);
    bNx[r] = 2.f * L2E * bi[128 + mu + r];
    bNh[r] = 2.f * L2E * bh[128 + mu + r];
  }
  f4 h = {0.f, 0.f, 0.f, 0.f};

  // layer-0 per-lane x prefetch (batch row b0+n15)
  const size_t xrow = (size_t)(b0 + n15);
  float px0 = 0.f, px1 = 0.f, px2 = 0.f, px3 = 0.f;
  if (g == 0) {
    if (stack) { f4 t4 = *(const f4*)(xp + xrow * TT * 4); px0 = t4[0]; px1 = t4[1]; px2 = t4[2]; px3 = t4[3]; }
    else       { px0 = xs[xrow * TT]; }
  }

// One timestep; S is a compile-time ring-slot literal. Order: x-path first
// (producer usually ahead -> overlaps peers finishing), then peer sync + h.
#define GRU_BODY(S)                                                            \
  {                                                                            \
    constexpr int SW = (S + 1) & 3;                                            \
    f4 aR = bR, aZ = bZ, aNx = bNx, aNh = bNh;                                 \
    if (g == 0) {                                                              \
      bf8 xq;                                                                  \
      _Pragma("unroll") for (int j = 0; j < 8; ++j) xq[j] = 0;                 \
      if (q == 0) {                                                            \
        if (stack) {                                                           \
          short a0 = (short)f2bf_rne(px0), a1 = (short)f2bf_rne(px1);          \
          short a2 = (short)f2bf_rne(px2), a3 = (short)f2bf_rne(px3);          \
          xq[0] = a0; xq[1] = a1; xq[2] = a2; xq[3] = a3;                      \
          xq[4] = a0; xq[5] = a1; xq[6] = a2; xq[7] = a3;                      \
        } else {                                                               \
          unsigned short xh = f2bf_rne(px0);                                   \
          float xf = __uint_as_float((unsigned)xh << 16);                      \
          unsigned short xl = f2bf_rne(px0 - xf);                              \
          xq[0] = (short)xh; xq[1] = (short)xl;                                \
          xq[4] = (short)xh; xq[5] = (short)xl;                                \
        }                                                                      \
      }                                                                        \
      __builtin_amdgcn_s_setprio(1);                                           \
      aR  = MFMA16(wxh_[0][0], xq, aR);                                        \
      aZ  = MFMA16(wxh_[1][0], xq, aZ);                                        \
      aNx = MFMA16(wxh_[2][0], xq, aNx);                                       \
      __builtin_amdgcn_s_setprio(0);                                           \
      if (tc + 1 < TT) {                                                       \
        if (stack) { f4 t4 = *(const f4*)(xp + (xrow * TT + tc + 1) * 4);      \
                     px0 = t4[0]; px1 = t4[1]; px2 = t4[2]; px3 = t4[3]; }     \
        else       { px0 = xs[xrow * TT + tc + 1]; }                           \
      }                                                                        \
    } else {                                                                   \
      waitq(&qdone[g - 1], 4u * (unsigned)(tc + 1));                           \
      bf8 xc0 = *(const bf8*)&hb[g - 1][SW][q][n15][0];                        \
      bf8 xc1 = *(const bf8*)&hb[g - 1][SW][4 + q][n15][0];                    \
      __builtin_amdgcn_s_setprio(1);                                           \
      aR  = MFMA16(wxh_[0][0], xc0, aR);  aR  = MFMA16(wxh_[0][1], xc1, aR);   \
      aZ  = MFMA16(wxh_[1][0], xc0, aZ);  aZ  = MFMA16(wxh_[1][1], xc1, aZ);   \
      aNx = MFMA16(wxh_[2][0], xc0, aNx); aNx = MFMA16(wxh_[2][1], xc1, aNx);  \
      __builtin_amdgcn_s_setprio(0);                                           \
    }                                                                          \
    waitq(&qdone[g], 4u * (unsigned)tc);                                       \
    bf8 hh0 = *(const bf8*)&hb[g][S][q][n15][0];                               \
    bf8 hh1 = *(const bf8*)&hb[g][S][4 + q][n15][0];                           \
    __builtin_amdgcn_s_setprio(1);                                             \
    aR  = MFMA16(whh_[0][0], hh0, aR);  aR  = MFMA16(whh_[0][1], hh1, aR);     \
    aZ  = MFMA16(whh_[1][0], hh0, aZ);  aZ  = MFMA16(whh_[1][1], hh1, aZ);     \
    aNh = MFMA16(whh_[2][0], hh0, aNh); aNh = MFMA16(whh_[2][1], hh1, aNh);    \
    __builtin_amdgcn_s_setprio(0);                                             \
    if (g < 3 && tc >= 4) waitq(&qdone[g + 1], 4u * (unsigned)(tc - 3));       \
    _Pragma("unroll") for (int r = 0; r < 4; ++r) {                            \
      float eR = __builtin_amdgcn_exp2f(-aR[r]);                               \
      float eZ = __builtin_amdgcn_exp2f(-aZ[r]);                               \
      float dR = 1.f + eR, dZ = 1.f + eZ;                                      \
      float qq = __builtin_amdgcn_rcpf(dR * dZ);                               \
      float rr = dZ * qq;   /* = 1/dR = sigmoid(aR) */                         \
      float zz = dR * qq;   /* = 1/dZ = sigmoid(aZ) */                         \
      float eN = __builtin_amdgcn_exp2f(aNx[r] + rr * aNh[r]);                 \
      float nn = 1.f - 2.f * __builtin_amdgcn_rcpf(eN + 1.f);                  \
      h[r] = nn + zz * (h[r] - nn);                                            \
    }                                                                          \
    unsigned p01, p23;                                                         \
    asm("v_cvt_pk_bf16_f32 %0, %1, %2" : "=v"(p01) : "v"(h[0]), "v"(h[1]));   \
    asm("v_cvt_pk_bf16_f32 %0, %1, %2" : "=v"(p23) : "v"(h[2]), "v"(h[3]));   \
    u32x2 hiw = {p01, p23};                                                    \
    *(u32x2*)&hb[g][SW][fr_w][n15][eo_w] = hiw;                                \
    if (g == 3 && tc == TT - 1)                                                \
      *(f4*)&hlast[((size_t)stack * BB + b0 + n15) * 64 + mu] = h;             \
    if (lane == 0)                                                             \
      __hip_atomic_fetch_add(&qdone[g], 1u, __ATOMIC_RELEASE,                  \
                             __HIP_MEMORY_SCOPE_WORKGROUP);                    \
  }

  for (int t = 0; t < TT; t += 4) {
    { const int tc = t;     GRU_BODY(0) }
    { const int tc = t + 1; GRU_BODY(1) }
    { const int tc = t + 2; GRU_BODY(2) }
    { const int tc = t + 3; GRU_BODY(3) }
  }
#undef GRU_BODY
}

// ---------------- FC head ----------------
__global__ __launch_bounds__(128) void head(
    const float* __restrict__ hlast,
    const float* __restrict__ W1, const float* __restrict__ b1,
    const float* __restrict__ g1, const float* __restrict__ be1,
    const float* __restrict__ m1, const float* __restrict__ v1,
    const float* __restrict__ W2, const float* __restrict__ b2,
    const float* __restrict__ g2, const float* __restrict__ be2,
    const float* __restrict__ m2, const float* __restrict__ v2,
    const float* __restrict__ W3, const float* __restrict__ b3,
    float* __restrict__ out) {
  const int b = blockIdx.x;
  const int j = threadIdx.x;
  __shared__ float xin[128];
  __shared__ float y1[128];
  __shared__ float y2[128];
  xin[j] = (j < 64) ? hlast[(size_t)b * 64 + j]
                    : hlast[(size_t)BB * 64 + (size_t)b * 64 + (j - 64)];
  __syncthreads();
  float acc = b1[j];
  #pragma unroll 8
  for (int k = 0; k < 128; ++k) acc = fmaf(W1[j * 128 + k], xin[k], acc);
  float sc = g1[j] * rsqrtf(v1[j] + 1e-5f);
  y1[j] = fmaxf(0.f, (acc - m1[j]) * sc + be1[j]);
  __syncthreads();
  acc = b2[j];
  #pragma unroll 8
  for (int k = 0; k < 128; ++k) acc = fmaf(W2[j * 128 + k], y1[k], acc);
  sc = g2[j] * rsqrtf(v2[j] + 1e-5f);
  y2[j] = fmaxf(0.f, (acc - m2[j]) * sc + be2[j]);
  __syncthreads();
  if (j < 2) {
    float a = b3[j];
    #pragma unroll 8
    for (int k = 0; k < 128; ++k) a = fmaf(W3[j * 128 + k], y2[k], a);
    out[(size_t)b * 2 + j] = a;
  }
}

}  // namespace

extern "C" void kernel_launch(void* const* d_in, const int* in_sizes, int n_in,
                              void* d_out, int out_size, void* d_ws, size_t ws_size,
                              hipStream_t stream) {
  (void)in_sizes; (void)n_in; (void)out_size; (void)ws_size;
  const float* sent   = (const float*)d_in[0];
  const float* price  = (const float*)d_in[1];
  const float* s_Wih0 = (const float*)d_in[2];
  const float* s_Wih  = (const float*)d_in[3];
  const float* s_Whh  = (const float*)d_in[4];
  const float* s_bih  = (const float*)d_in[5];
  const float* s_bhh  = (const float*)d_in[6];
  const float* p_Wih0 = (const float*)d_in[7];
  const float* p_Wih  = (const float*)d_in[8];
  const float* p_Whh  = (const float*)d_in[9];
  const float* p_bih  = (const float*)d_in[10];
  const float* p_bhh  = (const float*)d_in[11];
  const float* fc1_W  = (const float*)d_in[12];
  const float* fc1_b  = (const float*)d_in[13];
  const float* bn1_g  = (const float*)d_in[14];
  const float* bn1_b  = (const float*)d_in[15];
  const float* bn1_m  = (const float*)d_in[16];
  const float* bn1_v  = (const float*)d_in[17];
  const float* fc2_W  = (const float*)d_in[18];
  const float* fc2_b  = (const float*)d_in[19];
  const float* bn2_g  = (const float*)d_in[20];
  const float* bn2_b  = (const float*)d_in[21];
  const float* bn2_m  = (const float*)d_in[22];
  const float* bn2_v  = (const float*)d_in[23];
  const float* fc3_W  = (const float*)d_in[24];
  const float* fc3_b  = (const float*)d_in[25];
  float* out = (float*)d_out;

  float* hlast = (float*)d_ws;  // [2, B, 64] f32

  gru_all<<<dim3(256), dim3(1024), 0, stream>>>(
      sent, price, s_Wih0, p_Wih0, s_Wih, p_Wih, s_Whh, p_Whh,
      s_bih, p_bih, s_bhh, p_bhh, hlast);

  head<<<dim3(BB), dim3(128), 0, stream>>>(
      hlast, fc1_W, fc1_b, bn1_g, bn1_b, bn1_m, bn1_v,
      fc2_W, fc2_b, bn2_g, bn2_b, bn2_m, bn2_v, fc3_W, fc3_b, out);
}